// Round 6
// baseline (374.318 us; speedup 1.0000x reference)
//
#include <hip/hip_runtime.h>
#include <hip/hip_bf16.h>

typedef __hip_bfloat16 bf16h;
typedef short bf16x8 __attribute__((ext_vector_type(8)));
typedef float f32x4 __attribute__((ext_vector_type(4)));

#define NH 12
#define CHD 16
#define PQN 4
#define PVN 8
#define CSD 384
#define CZD 128
#define NN 512
#define HC 192
#define OUTD 2112
#define NSQ (NN*NN)
#define NPROJ 1152

// ws layout (float offsets). RAW/SB/WCT are consumed by k_proj_epi before k_row
// runs. Scores live entirely in LDS inside k_row (no HBM round-trip).
#define OFF_Q    0u
#define OFF_K    98304u
#define OFF_V    196608u
#define OFF_QP   294912u
#define OFF_KP   368640u
#define OFF_VP   442368u
#define OFF_RAW  589824u     /* f32 512x1152 = 589824 floats -> ends 1179648 */
#define OFF_SB   1179648u    /* bf16 512x384  = 98304 floats -> ends 1277952 */
#define OFF_WCT  1277952u    /* bf16 1152x384 = 221184 floats -> ends 1499136 */
#define OFF_CATB 3735552u    /* bf16 512x2112 = 540672 floats */
#define OFF_WOT  4276224u    /* bf16 384x2112 = 405504 floats */
#define OFF_BCAT 4681728u    /* f32 1152 -> end 4682880 floats = 18.73 MB */

// k_wcat block budget: 432 WCT tiles + 792 WoutT tiles + 128 s-pack + 1 bias
#define NT_WCT  432          /* (NPROJ/32)*(CSD/32) */
#define NT_WOUT 792          /* (OUTD/32)*(CSD/32)  */
#define WCAT_BLOCKS (NT_WCT + NT_WOUT + 128 + 1)

// k_row dynamic LDS: double-buffered z chunk staging, stride 18 (8B-aligned rows)
#define ZTS 18
#define KROW_LDS_BYTES (2*512*ZTS*4)   /* 73728 B; 2 blocks/CU: 154 KB < 160 */

// ---------------- Kernel W1: pack weights/s to bf16 (LDS-tiled transposes) ----------------
// R4 lesson: the Wqp/Wkvp boundary (col 720) is NOT 32-aligned -> matrix
// selection must be per-COLUMN (per-lane), not per-tile.
__global__ __launch_bounds__(256) void k_wcat(
    const float* __restrict__ s,
    const float* __restrict__ Wq, const float* __restrict__ bq,
    const float* __restrict__ Wkv, const float* __restrict__ bkv,
    const float* __restrict__ Wqp, const float* __restrict__ bqp,
    const float* __restrict__ Wkvp, const float* __restrict__ bkvp,
    const float* __restrict__ Wout, float* __restrict__ ws)
{
  __shared__ float tile[32][33];
  const int b = blockIdx.x, t = threadIdx.x;
  const int tx = t & 31, ty = t >> 5;        // 32 x 8
  if (b < NT_WCT) {
    // WcatT[col][c] = W[c][colW], tiles of 32 cols x 32 c
    const int ct = b / 12, rt = b % 12;
    const int col0 = ct*32, c0 = rt*32;
    const int col = col0 + tx;               // per-lane matrix select (720 boundary!)
    const float* W; int ld, colW;
    if (col < 192)      { W = Wq;   ld = 192; colW = col; }
    else if (col < 576) { W = Wkv;  ld = 384; colW = col-192; }
    else if (col < 720) { W = Wqp;  ld = 144; colW = col-576; }
    else                { W = Wkvp; ld = 432; colW = col-720; }
    #pragma unroll
    for (int r = 0; r < 4; ++r)
      tile[ty + r*8][tx] = W[(size_t)(c0 + ty + r*8)*ld + colW];
    __syncthreads();
    bf16h* dstW = (bf16h*)(ws + OFF_WCT);
    #pragma unroll
    for (int r = 0; r < 4; ++r) {
      int colL = ty + r*8;
      dstW[(size_t)(col0 + colL)*CSD + c0 + tx] = __float2bfloat16(tile[tx][colL]);
    }
  } else if (b < NT_WCT + NT_WOUT) {
    // WoutT[n][k] = Wout[k][n], tiles of 32 k x 32 n
    const int q = b - NT_WCT;
    const int kt = q / 12, nt2 = q % 12;
    const int k0 = kt*32, n0 = nt2*32;
    #pragma unroll
    for (int r = 0; r < 4; ++r)
      tile[ty + r*8][tx] = Wout[(size_t)(k0 + ty + r*8)*CSD + n0 + tx];
    __syncthreads();
    bf16h* woutT = (bf16h*)(ws + OFF_WOT);
    #pragma unroll
    for (int r = 0; r < 4; ++r) {
      int nL = ty + r*8;
      woutT[(size_t)(n0 + nL)*OUTD + k0 + tx] = __float2bfloat16(tile[tx][nL]);
    }
  } else if (b < NT_WCT + NT_WOUT + 128) {
    const int n0 = (b - (NT_WCT + NT_WOUT))*4;
    bf16h* sb = (bf16h*)(ws + OFF_SB);
    for (int idx = t; idx < 4*CSD; idx += 256)
      sb[(size_t)n0*CSD + idx] = __float2bfloat16(s[(size_t)n0*CSD + idx]);
  } else {
    float* bcat = ws + OFF_BCAT;
    for (int o = t; o < NPROJ; o += 256) {
      float v;
      if (o < 192)      v = bq[o];
      else if (o < 576) v = bkv[o-192];
      else if (o < 720) v = bqp[o-576];
      else              v = bkvp[o-720];
      bcat[o] = v;
    }
  }
}

// ---------------- Kernel A1: raw = sb @ WcatT^T via MFMA ----------------
__global__ __launch_bounds__(256) void k_proj_gemm(float* __restrict__ ws)
{
  const bf16h* sb    = (const bf16h*)(ws + OFF_SB);
  const bf16h* wcatT = (const bf16h*)(ws + OFF_WCT);
  float* raw = ws + OFF_RAW;
  const int t = threadIdx.x;
  const int wave = t >> 6, lane = t & 63;
  const int m0 = blockIdx.x*32 + (wave>>1)*16;
  const int n0 = blockIdx.y*32 + (wave&1)*16;
  const int lm = lane & 15, quad = lane >> 4;
  const bf16x8* pa = (const bf16x8*)(sb    + (size_t)(m0+lm)*CSD) + quad;
  const bf16x8* pb = (const bf16x8*)(wcatT + (size_t)(n0+lm)*CSD) + quad;
  f32x4 acc = {0.f, 0.f, 0.f, 0.f};
  #pragma unroll
  for (int kk = 0; kk < CSD/32; ++kk) {
    bf16x8 av = pa[kk*4];
    bf16x8 bv = pb[kk*4];
    acc = __builtin_amdgcn_mfma_f32_16x16x32_bf16(av, bv, acc, 0, 0, 0);
  }
  const int col = n0 + lm;
  #pragma unroll
  for (int r = 0; r < 4; ++r) {
    int row = m0 + quad*4 + r;
    raw[(size_t)row*NPROJ + col] = acc[r];
  }
}

// ---------------- Kernel A2: bias + scatter + point rotation (4 rows/block) ----------------
#define RPB 4
__global__ __launch_bounds__(256) void k_proj_epi(
    const float* __restrict__ rot, const float* __restrict__ trans,
    float* __restrict__ ws)
{
  __shared__ float praw[RPB][576];
  const int n0 = blockIdx.x*RPB, t = threadIdx.x;
  const float* raw = ws + OFF_RAW;
  const float* bcat = ws + OFF_BCAT;
  for (int idx = t; idx < RPB*NPROJ; idx += 256) {
    int r = idx / NPROJ, o = idx - r*NPROJ;
    int n = n0 + r;
    float v = raw[(size_t)n*NPROJ + o] + bcat[o];
    if (o < 192) {
      ws[OFF_Q + n*HC + o] = v;
    } else if (o < 576) {
      int col = o-192, h = col >> 5, rr = col & 31;
      if (rr < CHD) ws[OFF_K + n*HC + h*CHD + rr] = v;
      else          ws[OFF_V + n*HC + h*CHD + (rr-CHD)] = v;
    } else {
      praw[r][o-576] = v;
    }
  }
  __syncthreads();
  for (int m2 = t; m2 < RPB*192; m2 += 256) {
    int r = m2 / 192, m = m2 % 192;
    int n = n0 + r;
    float g0, g1, g2; float* dst;
    if (m < 48) {
      g0 = praw[r][m]; g1 = praw[r][48+m]; g2 = praw[r][96+m];
      int h = m >> 2, p = m & 3;
      dst = ws + OFF_QP + ((n*NH+h)*PQN + p)*3;
    } else {
      int mm = m - 48;
      g0 = praw[r][144+mm]; g1 = praw[r][288+mm]; g2 = praw[r][432+mm];
      int h = mm / 12, pp = mm % 12;
      if (pp < PQN) dst = ws + OFF_KP + ((n*NH+h)*PQN + pp)*3;
      else          dst = ws + OFF_VP + ((n*NH+h)*PVN + (pp-PQN))*3;
    }
    #pragma unroll
    for (int x = 0; x < 3; ++x)
      dst[x] = rot[n*9+x*3+0]*g0 + rot[n*9+x*3+1]*g1 + rot[n*9+x*3+2]*g2 + trans[n*3+x];
  }
}

// ---------------- Kernel R: full per-row pipeline ----------------
// One block per row i, 512 threads. R5 lessons applied:
//  - phase 1: double-buffered z chunks (dynamic LDS, 1 barrier/chunk instead of 2),
//    stride-18 rows (8B-aligned) so LDS traffic is b64 not b32.
//  - phase 3: 3a and 3b merged into one j-loop, unroll x8 (LDS+global ILP).
__global__ __launch_bounds__(512) void k_row(
    const float* __restrict__ z, const float* __restrict__ Wb, const float* __restrict__ bbp,
    const float* __restrict__ mask, const float* __restrict__ head_w,
    const float* __restrict__ rot, const float* __restrict__ trans,
    float* __restrict__ ws)
{
  extern __shared__ float uzt[];   // [2][512*ZTS] phase1 dbuf; phase2/3: a[h][520]
  __shared__ float ql[HC];
  __shared__ float qpl[144];
  __shared__ float hwl[NH];
  __shared__ float redM[NH][8];
  __shared__ float redS[NH][8];
  __shared__ float optl[288];
  const int t = threadIdx.x, i = blockIdx.x;
  const int wave = t >> 6, lane = t & 63;

  if (t < HC)           ql[t]     = ws[OFF_Q  + (size_t)i*HC  + t];
  else if (t < HC+144)  qpl[t-HC] = ws[OFF_QP + (size_t)i*144 + (t-HC)];
  else if (t >= 352 && t < 352+NH)
    hwl[t-352] = log1pf(expf(head_w[t-352])) * 0.13608276348795434f; // softplus*sqrt(1/54)

  // ---- phase 1: b_pair accumulation (z HBM stream, 8 chunks x 16 ch, dbuf) ----
  float acc[NH];
  #pragma unroll
  for (int h = 0; h < NH; ++h) acc[h] = bbp[h];
  float4 pf[4];
  #pragma unroll
  for (int k = 0; k < 4; ++k) {
    int idx4 = k*512 + t;
    int row = idx4 >> 2, c4 = idx4 & 3;
    pf[k] = *(const float4*)(z + ((size_t)i*NN + row)*CZD + c4*4);
  }
  for (int cb = 0; cb < 8; ++cb) {
    float* ztw = uzt + (cb & 1)*(512*ZTS);
    // write current chunk (held in pf) into its buffer. Safe without a pre-barrier:
    // readers of this buffer ran in iteration cb-2, and iteration cb-1's barrier
    // ordered them before this write.
    #pragma unroll
    for (int k = 0; k < 4; ++k) {
      int idx4 = k*512 + t;
      int row = idx4 >> 2, c4 = idx4 & 3;
      float* d = ztw + row*ZTS + c4*4;
      *(float2*)(d)     = make_float2(pf[k].x, pf[k].y);
      *(float2*)(d + 2) = make_float2(pf[k].z, pf[k].w);
    }
    if (cb < 7) {
      #pragma unroll
      for (int k = 0; k < 4; ++k) {
        int idx4 = k*512 + t;
        int row = idx4 >> 2, c4 = idx4 & 3;
        pf[k] = *(const float4*)(z + ((size_t)i*NN + row)*CZD + (cb+1)*16 + c4*4);
      }
    }
    __syncthreads();
    const float* ztr = ztw;
    #pragma unroll
    for (int c2 = 0; c2 < 8; ++c2) {
      float2 v = *(const float2*)(ztr + t*ZTS + c2*2);
      const float* w0 = Wb + (cb*16 + c2*2)*NH;   // wave-uniform -> scalar loads
      #pragma unroll
      for (int h = 0; h < NH; ++h) acc[h] += v.x*w0[h] + v.y*w0[NH+h];
    }
  }

  // ---- phase 2: scores + softmax, 3 groups of 4 heads (6 barriers total) ----
  const float sc13  = 0.57735026918962576f;   // sqrt(1/3)
  const float sc_qk = 0.14433756729740643f;   // sqrt(1/48)
  const float mbias = 100000.0f*(mask[i]*mask[t] - 1.0f);
  #define AL(h,j) uzt[(h)*520 + (j)]
  for (int g = 0; g < 3; ++g) {
    float sc4[4];
    #pragma unroll
    for (int u = 0; u < 4; ++u) {
      const int h = g*4 + u;
      const f32x4* kr4 = (const f32x4*)(ws + OFF_K + (size_t)t*HC + h*CHD);
      const f32x4* qr4 = (const f32x4*)(ql + h*CHD);
      float dot = 0.f;
      #pragma unroll
      for (int v4 = 0; v4 < 4; ++v4) {
        f32x4 kv = kr4[v4], qv = qr4[v4];
        dot += qv[0]*kv[0] + qv[1]*kv[1] + qv[2]*kv[2] + qv[3]*kv[3];
      }
      const f32x4* kp4 = (const f32x4*)(ws + OFF_KP + (size_t)t*144 + h*12);
      const f32x4* qp4 = (const f32x4*)(qpl + h*12);
      float d2 = 0.f;
      #pragma unroll
      for (int v4 = 0; v4 < 3; ++v4) {
        f32x4 kv = kp4[v4], qv = qp4[v4];
        float d0 = qv[0]-kv[0], d1 = qv[1]-kv[1], dd2 = qv[2]-kv[2], d3 = qv[3]-kv[3];
        d2 += d0*d0 + d1*d1 + dd2*dd2 + d3*d3;
      }
      float scv = dot*sc_qk + acc[h]*sc13 - 0.5f*hwl[h]*d2 + mbias;
      float mv = scv;
      for (int off = 32; off > 0; off >>= 1) mv = fmaxf(mv, __shfl_xor(mv, off));
      if (lane == 0) redM[h][wave] = mv;
      sc4[u] = scv;
    }
    __syncthreads();
    #pragma unroll
    for (int u = 0; u < 4; ++u) {
      const int h = g*4 + u;
      float mv = redM[h][0];
      #pragma unroll
      for (int w = 1; w < 8; ++w) mv = fmaxf(mv, redM[h][w]);
      float e = expf(sc4[u] - mv);
      sc4[u] = e;
      float sv = e;
      for (int off = 32; off > 0; off >>= 1) sv += __shfl_xor(sv, off);
      if (lane == 0) redS[h][wave] = sv;
    }
    __syncthreads();
    #pragma unroll
    for (int u = 0; u < 4; ++u) {
      const int h = g*4 + u;
      float sv = redS[h][0];
      #pragma unroll
      for (int w = 1; w < 8; ++w) sv += redS[h][w];
      AL(h, t) = sc4[u]*(1.0f/sv);
    }
  }
  __syncthreads();                   // a fully written before cross-thread reads

  // ---- phase 3 (merged): o_pair (all threads) + o/o_pt (t<480) in one j-loop ----
  {
    const int hg = t >> 7, c = t & 127, h0 = hg*3;
    int hsel, off, stride; const float* src;
    if (t < 192)      { hsel = t >> 4;      src = ws + OFF_V;  off = t;     stride = HC;  }
    else if (t < 480) { hsel = (t-192)/24;  src = ws + OFF_VP; off = t-192; stride = 288; }
    else              { hsel = 0;           src = ws + OFF_V;  off = 0;     stride = HC;  }
    float oa0 = 0.f, oa1 = 0.f, oa2 = 0.f, ob = 0.f;
    const float* zrow = z + ((size_t)i*NN)*CZD + c;
    #pragma unroll 2
    for (int jj = 0; jj < NN; jj += 8) {
      f32x4 p00 = *(const f32x4*)(&AL(h0+0, jj));
      f32x4 p01 = *(const f32x4*)(&AL(h0+0, jj+4));
      f32x4 p10 = *(const f32x4*)(&AL(h0+1, jj));
      f32x4 p11 = *(const f32x4*)(&AL(h0+1, jj+4));
      f32x4 p20 = *(const f32x4*)(&AL(h0+2, jj));
      f32x4 p21 = *(const f32x4*)(&AL(h0+2, jj+4));
      f32x4 pb0 = *(const f32x4*)(&AL(hsel, jj));
      f32x4 pb1 = *(const f32x4*)(&AL(hsel, jj+4));
      float zv[8], vv[8];
      #pragma unroll
      for (int k2 = 0; k2 < 8; ++k2) zv[k2] = zrow[(size_t)(jj+k2)*CZD];
      #pragma unroll
      for (int k2 = 0; k2 < 8; ++k2) vv[k2] = src[(size_t)(jj+k2)*stride + off];
      oa0 += p00[0]*zv[0]+p00[1]*zv[1]+p00[2]*zv[2]+p00[3]*zv[3]
           + p01[0]*zv[4]+p01[1]*zv[5]+p01[2]*zv[6]+p01[3]*zv[7];
      oa1 += p10[0]*zv[0]+p10[1]*zv[1]+p10[2]*zv[2]+p10[3]*zv[3]
           + p11[0]*zv[4]+p11[1]*zv[5]+p11[2]*zv[6]+p11[3]*zv[7];
      oa2 += p20[0]*zv[0]+p20[1]*zv[1]+p20[2]*zv[2]+p20[3]*zv[3]
           + p21[0]*zv[4]+p21[1]*zv[5]+p21[2]*zv[6]+p21[3]*zv[7];
      ob  += pb0[0]*vv[0]+pb0[1]*vv[1]+pb0[2]*vv[2]+pb0[3]*vv[3]
           + pb1[0]*vv[4]+pb1[1]*vv[5]+pb1[2]*vv[6]+pb1[3]*vv[7];
    }
    bf16h* catb = (bf16h*)(ws + OFF_CATB);
    bf16h* dst = catb + (size_t)i*OUTD + 576;
    dst[(h0+0)*CZD + c] = __float2bfloat16(oa0);
    dst[(h0+1)*CZD + c] = __float2bfloat16(oa1);
    dst[(h0+2)*CZD + c] = __float2bfloat16(oa2);
    if (t < 192)      catb[(size_t)i*OUTD + t] = __float2bfloat16(ob);
    else if (t < 480) optl[t-192] = ob;
    __syncthreads();
    if (t < 96) {
      const int m = t, h = m >> 3;
      float g[3], Tl[3];
      #pragma unroll
      for (int y = 0; y < 3; ++y) { g[y] = optl[h*24 + (m&7)*3 + y]; Tl[y] = trans[i*3+y]; }
      float nrm = 1e-8f;
      float loc[3];
      #pragma unroll
      for (int x = 0; x < 3; ++x) {
        float v = 0.f;
        #pragma unroll
        for (int y = 0; y < 3; ++y) v += rot[i*9 + y*3 + x] * (g[y]-Tl[y]);
        loc[x] = v; nrm += v*v;
      }
      nrm = sqrtf(nrm);
      bf16h* crow = catb + (size_t)i*OUTD;
      crow[192 + 0*96 + m] = __float2bfloat16(loc[0]);
      crow[192 + 1*96 + m] = __float2bfloat16(loc[1]);
      crow[192 + 2*96 + m] = __float2bfloat16(loc[2]);
      crow[480 + m]        = __float2bfloat16(nrm);
    }
  }
  #undef AL
}

// ---------------- Kernel F: out = catb @ WoutT^T + bout via MFMA ----------------
__global__ __launch_bounds__(256) void k_out_mfma(
    const float* __restrict__ bout, const float* __restrict__ ws_c, float* __restrict__ out)
{
  const bf16h* catb  = (const bf16h*)(ws_c + OFF_CATB);
  const bf16h* woutT = (const bf16h*)(ws_c + OFF_WOT);
  const int t = threadIdx.x;
  const int wave = t >> 6, lane = t & 63;
  const int m0 = blockIdx.x*32 + (wave>>1)*16;
  const int n0 = blockIdx.y*32 + (wave&1)*16;
  const int lm = lane & 15, quad = lane >> 4;
  const bf16x8* pa = (const bf16x8*)(catb  + (size_t)(m0+lm)*OUTD) + quad;
  const bf16x8* pb = (const bf16x8*)(woutT + (size_t)(n0+lm)*OUTD) + quad;
  f32x4 acc = {0.f, 0.f, 0.f, 0.f};
  #pragma unroll 4
  for (int kk = 0; kk < OUTD/32; ++kk) {
    bf16x8 av = pa[kk*4];
    bf16x8 bv = pb[kk*4];
    acc = __builtin_amdgcn_mfma_f32_16x16x32_bf16(av, bv, acc, 0, 0, 0);
  }
  const int col = n0 + lm;
  const float bb = bout[col];
  #pragma unroll
  for (int r = 0; r < 4; ++r) {
    int row = m0 + quad*4 + r;
    out[(size_t)row*CSD + col] = acc[r] + bb;
  }
}

extern "C" void kernel_launch(void* const* d_in, const int* in_sizes, int n_in,
                              void* d_out, int out_size, void* d_ws, size_t ws_size,
                              hipStream_t stream)
{
  const float* s     = (const float*)d_in[0];
  const float* z     = (const float*)d_in[1];
  const float* rot   = (const float*)d_in[2];
  const float* trans = (const float*)d_in[3];
  const float* mask  = (const float*)d_in[4];
  const float* Wq    = (const float*)d_in[5];
  const float* bq    = (const float*)d_in[6];
  const float* Wkv   = (const float*)d_in[7];
  const float* bkv   = (const float*)d_in[8];
  const float* Wqp   = (const float*)d_in[9];
  const float* bqp   = (const float*)d_in[10];
  const float* Wkvp  = (const float*)d_in[11];
  const float* bkvp  = (const float*)d_in[12];
  const float* Wb    = (const float*)d_in[13];
  const float* bb    = (const float*)d_in[14];
  const float* hwts  = (const float*)d_in[15];
  const float* Wout  = (const float*)d_in[16];
  const float* bout  = (const float*)d_in[17];
  float* ws  = (float*)d_ws;
  float* out = (float*)d_out;

  hipLaunchKernelGGL(k_wcat, dim3(WCAT_BLOCKS), dim3(256), 0, stream,
                     s, Wq, bq, Wkv, bkv, Wqp, bqp, Wkvp, bkvp, Wout, ws);
  hipLaunchKernelGGL(k_proj_gemm, dim3(NN/32, NPROJ/32), dim3(256), 0, stream, ws);
  hipLaunchKernelGGL(k_proj_epi,  dim3(NN/RPB), dim3(256), 0, stream, rot, trans, ws);
  hipLaunchKernelGGL(k_row, dim3(NN), dim3(512), KROW_LDS_BYTES, stream,
                     z, Wb, bb, mask, hwts, rot, trans, ws);
  hipLaunchKernelGGL(k_out_mfma, dim3(NN/32, CSD/32), dim3(256), 0, stream, bout, ws, out);
}

// Round 7
// 331.712 us; speedup vs baseline: 1.1284x; 1.1284x over previous
//
#include <hip/hip_runtime.h>
#include <hip/hip_bf16.h>

typedef __hip_bfloat16 bf16h;
typedef short bf16x8 __attribute__((ext_vector_type(8)));
typedef float f32x4 __attribute__((ext_vector_type(4)));

#define NH 12
#define CHD 16
#define PQN 4
#define PVN 8
#define CSD 384
#define CZD 128
#define NN 512
#define HC 192
#define OUTD 2112
#define NSQ (NN*NN)
#define NPROJ 1152

// ws layout (float offsets). RAW/SB/WCT are consumed by k_proj_epi before k_row
// runs. Scores live entirely in LDS inside k_row (no HBM round-trip).
// K and KP are stored TRANSPOSED ([h][c][j]) so k_row phase-2 reads coalesce.
#define OFF_Q    0u
#define OFF_K    98304u      /* f32 [12][16][512] = 98304 floats (transposed) */
#define OFF_V    196608u     /* f32 [n][h*16+c] row-major (phase-3b coalesced) */
#define OFF_QP   294912u     /* f32 [n][144] */
#define OFF_KP   368640u     /* f32 [12][12][512] = 73728 floats (transposed) */
#define OFF_VP   442368u     /* f32 [n][288] */
#define OFF_RAW  589824u     /* f32 512x1152 = 589824 floats -> ends 1179648 */
#define OFF_SB   1179648u    /* bf16 512x384  = 98304 floats -> ends 1277952 */
#define OFF_WCT  1277952u    /* bf16 1152x384 = 221184 floats -> ends 1499136 */
#define OFF_CATB 3735552u    /* bf16 512x2112 = 540672 floats */
#define OFF_WOT  4276224u    /* bf16 384x2112 = 405504 floats */
#define OFF_BCAT 4681728u    /* f32 1152 -> end 4682880 floats = 18.73 MB */

// k_wcat block budget: 432 WCT tiles + 792 WoutT tiles + 128 s-pack + 1 bias
#define NT_WCT  432          /* (NPROJ/32)*(CSD/32) */
#define NT_WOUT 792          /* (OUTD/32)*(CSD/32)  */
#define WCAT_BLOCKS (NT_WCT + NT_WOUT + 128 + 1)

// ---------------- Kernel W1: pack weights/s to bf16 (LDS-tiled transposes) ----------------
// R4 lesson: the Wqp/Wkvp boundary (col 720) is NOT 32-aligned -> matrix
// selection must be per-COLUMN (per-lane), not per-tile.
__global__ __launch_bounds__(256) void k_wcat(
    const float* __restrict__ s,
    const float* __restrict__ Wq, const float* __restrict__ bq,
    const float* __restrict__ Wkv, const float* __restrict__ bkv,
    const float* __restrict__ Wqp, const float* __restrict__ bqp,
    const float* __restrict__ Wkvp, const float* __restrict__ bkvp,
    const float* __restrict__ Wout, float* __restrict__ ws)
{
  __shared__ float tile[32][33];
  const int b = blockIdx.x, t = threadIdx.x;
  const int tx = t & 31, ty = t >> 5;        // 32 x 8
  if (b < NT_WCT) {
    // WcatT[col][c] = W[c][colW], tiles of 32 cols x 32 c
    const int ct = b / 12, rt = b % 12;
    const int col0 = ct*32, c0 = rt*32;
    const int col = col0 + tx;               // per-lane matrix select (720 boundary!)
    const float* W; int ld, colW;
    if (col < 192)      { W = Wq;   ld = 192; colW = col; }
    else if (col < 576) { W = Wkv;  ld = 384; colW = col-192; }
    else if (col < 720) { W = Wqp;  ld = 144; colW = col-576; }
    else                { W = Wkvp; ld = 432; colW = col-720; }
    #pragma unroll
    for (int r = 0; r < 4; ++r)
      tile[ty + r*8][tx] = W[(size_t)(c0 + ty + r*8)*ld + colW];
    __syncthreads();
    bf16h* dstW = (bf16h*)(ws + OFF_WCT);
    #pragma unroll
    for (int r = 0; r < 4; ++r) {
      int colL = ty + r*8;
      dstW[(size_t)(col0 + colL)*CSD + c0 + tx] = __float2bfloat16(tile[tx][colL]);
    }
  } else if (b < NT_WCT + NT_WOUT) {
    // WoutT[n][k] = Wout[k][n], tiles of 32 k x 32 n
    const int q = b - NT_WCT;
    const int kt = q / 12, nt2 = q % 12;
    const int k0 = kt*32, n0 = nt2*32;
    #pragma unroll
    for (int r = 0; r < 4; ++r)
      tile[ty + r*8][tx] = Wout[(size_t)(k0 + ty + r*8)*CSD + n0 + tx];
    __syncthreads();
    bf16h* woutT = (bf16h*)(ws + OFF_WOT);
    #pragma unroll
    for (int r = 0; r < 4; ++r) {
      int nL = ty + r*8;
      woutT[(size_t)(n0 + nL)*OUTD + k0 + tx] = __float2bfloat16(tile[tx][nL]);
    }
  } else if (b < NT_WCT + NT_WOUT + 128) {
    const int n0 = (b - (NT_WCT + NT_WOUT))*4;
    bf16h* sb = (bf16h*)(ws + OFF_SB);
    for (int idx = t; idx < 4*CSD; idx += 256)
      sb[(size_t)n0*CSD + idx] = __float2bfloat16(s[(size_t)n0*CSD + idx]);
  } else {
    float* bcat = ws + OFF_BCAT;
    for (int o = t; o < NPROJ; o += 256) {
      float v;
      if (o < 192)      v = bq[o];
      else if (o < 576) v = bkv[o-192];
      else if (o < 720) v = bqp[o-576];
      else              v = bkvp[o-720];
      bcat[o] = v;
    }
  }
}

// ---------------- Kernel A1: raw = sb @ WcatT^T via MFMA ----------------
__global__ __launch_bounds__(256) void k_proj_gemm(float* __restrict__ ws)
{
  const bf16h* sb    = (const bf16h*)(ws + OFF_SB);
  const bf16h* wcatT = (const bf16h*)(ws + OFF_WCT);
  float* raw = ws + OFF_RAW;
  const int t = threadIdx.x;
  const int wave = t >> 6, lane = t & 63;
  const int m0 = blockIdx.x*32 + (wave>>1)*16;
  const int n0 = blockIdx.y*32 + (wave&1)*16;
  const int lm = lane & 15, quad = lane >> 4;
  const bf16x8* pa = (const bf16x8*)(sb    + (size_t)(m0+lm)*CSD) + quad;
  const bf16x8* pb = (const bf16x8*)(wcatT + (size_t)(n0+lm)*CSD) + quad;
  f32x4 acc = {0.f, 0.f, 0.f, 0.f};
  #pragma unroll
  for (int kk = 0; kk < CSD/32; ++kk) {
    bf16x8 av = pa[kk*4];
    bf16x8 bv = pb[kk*4];
    acc = __builtin_amdgcn_mfma_f32_16x16x32_bf16(av, bv, acc, 0, 0, 0);
  }
  const int col = n0 + lm;
  #pragma unroll
  for (int r = 0; r < 4; ++r) {
    int row = m0 + quad*4 + r;
    raw[(size_t)row*NPROJ + col] = acc[r];
  }
}

// ---------------- Kernel A2: bias + scatter + point rotation (4 rows/block) ----------------
// K and KP now written TRANSPOSED: KT[(h*16+c)*512 + n], KPT[((h*4+p)*3+x)*512 + n]
// so k_row phase-2 per-thread (j=t) reads are wave-coalesced.
#define RPB 4
__global__ __launch_bounds__(256) void k_proj_epi(
    const float* __restrict__ rot, const float* __restrict__ trans,
    float* __restrict__ ws)
{
  __shared__ float praw[RPB][576];
  const int n0 = blockIdx.x*RPB, t = threadIdx.x;
  const float* raw = ws + OFF_RAW;
  const float* bcat = ws + OFF_BCAT;
  for (int idx = t; idx < RPB*NPROJ; idx += 256) {
    int r = idx / NPROJ, o = idx - r*NPROJ;
    int n = n0 + r;
    float v = raw[(size_t)n*NPROJ + o] + bcat[o];
    if (o < 192) {
      ws[OFF_Q + n*HC + o] = v;
    } else if (o < 576) {
      int col = o-192, h = col >> 5, rr = col & 31;
      if (rr < CHD) ws[OFF_K + (size_t)(h*CHD + rr)*NN + n] = v;   // transposed
      else          ws[OFF_V + n*HC + h*CHD + (rr-CHD)] = v;
    } else {
      praw[r][o-576] = v;
    }
  }
  __syncthreads();
  for (int m2 = t; m2 < RPB*192; m2 += 256) {
    int r = m2 / 192, m = m2 % 192;
    int n = n0 + r;
    float g0, g1, g2;
    if (m < 48) {
      g0 = praw[r][m]; g1 = praw[r][48+m]; g2 = praw[r][96+m];
      int h = m >> 2, p = m & 3;
      float* dst = ws + OFF_QP + ((size_t)n*NH+h)*PQN*3 + p*3;
      #pragma unroll
      for (int x = 0; x < 3; ++x)
        dst[x] = rot[n*9+x*3+0]*g0 + rot[n*9+x*3+1]*g1 + rot[n*9+x*3+2]*g2 + trans[n*3+x];
    } else {
      int mm = m - 48;
      g0 = praw[r][144+mm]; g1 = praw[r][288+mm]; g2 = praw[r][432+mm];
      int h = mm / 12, pp = mm % 12;
      if (pp < PQN) {
        #pragma unroll
        for (int x = 0; x < 3; ++x)
          ws[OFF_KP + (size_t)((h*PQN + pp)*3 + x)*NN + n] =       // transposed
            rot[n*9+x*3+0]*g0 + rot[n*9+x*3+1]*g1 + rot[n*9+x*3+2]*g2 + trans[n*3+x];
      } else {
        float* dst = ws + OFF_VP + ((size_t)n*NH+h)*PVN*3 + (pp-PQN)*3;
        #pragma unroll
        for (int x = 0; x < 3; ++x)
          dst[x] = rot[n*9+x*3+0]*g0 + rot[n*9+x*3+1]*g1 + rot[n*9+x*3+2]*g2 + trans[n*3+x];
      }
    }
  }
}

// ---------------- Kernel R: full per-row pipeline ----------------
// One block per row i, 512 threads. R6 lesson: dbuf-with-one-barrier loses
// (vmcnt(0) drain at barrier kills prefetch overlap) and even LDS strides
// conflict -> phase 1 restored to R5 exact (stride 17, 2 barriers).
// Phase 2 now reads TRANSPOSED K/KP: coalesced scalar loads, 28 independent
// per head (was 7 uncoalesced f32x4 -> 64 lines per wave-load).
__global__ __launch_bounds__(512) void k_row(
    const float* __restrict__ z, const float* __restrict__ Wb, const float* __restrict__ bbp,
    const float* __restrict__ mask, const float* __restrict__ head_w,
    const float* __restrict__ rot, const float* __restrict__ trans,
    float* __restrict__ ws)
{
  __shared__ float uzt[512*17];    // phase1: zt[row][17]; phase2/3: a[h][520]
  __shared__ float ql[HC];
  __shared__ float qpl[144];
  __shared__ float hwl[NH];
  __shared__ float redM[NH][8];
  __shared__ float redS[NH][8];
  __shared__ float optl[288];
  const int t = threadIdx.x, i = blockIdx.x;
  const int wave = t >> 6, lane = t & 63;

  if (t < HC)           ql[t]     = ws[OFF_Q  + (size_t)i*HC  + t];
  else if (t < HC+144)  qpl[t-HC] = ws[OFF_QP + (size_t)i*144 + (t-HC)];
  else if (t >= 352 && t < 352+NH)
    hwl[t-352] = log1pf(expf(head_w[t-352])) * 0.13608276348795434f; // softplus*sqrt(1/54)

  // ---- phase 1: b_pair accumulation (z HBM stream, 8 chunks x 16 ch) ----
  float acc[NH];
  #pragma unroll
  for (int h = 0; h < NH; ++h) acc[h] = bbp[h];
  float4 pf[4];
  #pragma unroll
  for (int k = 0; k < 4; ++k) {
    int idx4 = k*512 + t;
    int row = idx4 >> 2, c4 = idx4 & 3;
    pf[k] = *(const float4*)(z + ((size_t)i*NN + row)*CZD + c4*4);
  }
  for (int cb = 0; cb < 8; ++cb) {
    __syncthreads();
    #pragma unroll
    for (int k = 0; k < 4; ++k) {
      int idx4 = k*512 + t;
      int row = idx4 >> 2, c4 = idx4 & 3;
      float* d = uzt + row*17 + c4*4;
      d[0]=pf[k].x; d[1]=pf[k].y; d[2]=pf[k].z; d[3]=pf[k].w;
    }
    __syncthreads();
    if (cb < 7) {
      #pragma unroll
      for (int k = 0; k < 4; ++k) {
        int idx4 = k*512 + t;
        int row = idx4 >> 2, c4 = idx4 & 3;
        pf[k] = *(const float4*)(z + ((size_t)i*NN + row)*CZD + (cb+1)*16 + c4*4);
      }
    }
    #pragma unroll
    for (int c = 0; c < 16; ++c) {
      float v = uzt[t*17 + c];
      const float* w = Wb + (cb*16+c)*NH;   // wave-uniform -> scalar loads
      #pragma unroll
      for (int h = 0; h < NH; ++h) acc[h] += v*w[h];
    }
  }

  // ---- phase 2: scores + softmax, 3 groups of 4 heads (6 barriers total) ----
  const float sc13  = 0.57735026918962576f;   // sqrt(1/3)
  const float sc_qk = 0.14433756729740643f;   // sqrt(1/48)
  const float mbias = 100000.0f*(mask[i]*mask[t] - 1.0f);
  #define AL(h,j) uzt[(h)*520 + (j)]
  for (int g = 0; g < 3; ++g) {
    float sc4[4];
    #pragma unroll
    for (int u = 0; u < 4; ++u) {
      const int h = g*4 + u;
      const float* kt  = ws + OFF_K  + (size_t)(h*CHD)*NN + t;   // coalesced columns
      const float* kpt = ws + OFF_KP + (size_t)(h*12)*NN + t;
      float dot = 0.f;
      #pragma unroll
      for (int c = 0; c < CHD; ++c) dot += ql[h*CHD+c]*kt[(size_t)c*NN];
      float d2 = 0.f;
      #pragma unroll
      for (int e = 0; e < 12; ++e) { float d = qpl[h*12+e]-kpt[(size_t)e*NN]; d2 += d*d; }
      float scv = dot*sc_qk + acc[h]*sc13 - 0.5f*hwl[h]*d2 + mbias;
      float mv = scv;
      for (int off = 32; off > 0; off >>= 1) mv = fmaxf(mv, __shfl_xor(mv, off));
      if (lane == 0) redM[h][wave] = mv;
      sc4[u] = scv;
    }
    __syncthreads();
    #pragma unroll
    for (int u = 0; u < 4; ++u) {
      const int h = g*4 + u;
      float mv = redM[h][0];
      #pragma unroll
      for (int w = 1; w < 8; ++w) mv = fmaxf(mv, redM[h][w]);
      float e = expf(sc4[u] - mv);
      sc4[u] = e;
      float sv = e;
      for (int off = 32; off > 0; off >>= 1) sv += __shfl_xor(sv, off);
      if (lane == 0) redS[h][wave] = sv;
    }
    __syncthreads();
    #pragma unroll
    for (int u = 0; u < 4; ++u) {
      const int h = g*4 + u;
      float sv = redS[h][0];
      #pragma unroll
      for (int w = 1; w < 8; ++w) sv += redS[h][w];
      AL(h, t) = sc4[u]*(1.0f/sv);
    }
  }
  __syncthreads();                   // a fully written before cross-thread reads

  // ---- phase 3a: o_pair[h][c] = sum_j a[h][j]*z[i][j][c] (z from L2/L3) ----
  {
    const int hg = t >> 7, c = t & 127;   // 4 groups x 3 heads, one channel each
    const int h0 = hg*3;
    float oa0 = 0.f, oa1 = 0.f, oa2 = 0.f;
    const float* zrow = z + ((size_t)i*NN)*CZD + c;
    #pragma unroll 2
    for (int jj = 0; jj < NN; jj += 4) {
      f32x4 a0 = *(const f32x4*)(&AL(h0+0, jj));
      f32x4 a1 = *(const f32x4*)(&AL(h0+1, jj));
      f32x4 a2 = *(const f32x4*)(&AL(h0+2, jj));
      float z0 = zrow[(size_t)(jj+0)*CZD];
      float z1 = zrow[(size_t)(jj+1)*CZD];
      float z2 = zrow[(size_t)(jj+2)*CZD];
      float z3 = zrow[(size_t)(jj+3)*CZD];
      oa0 += a0[0]*z0 + a0[1]*z1 + a0[2]*z2 + a0[3]*z3;
      oa1 += a1[0]*z0 + a1[1]*z1 + a1[2]*z2 + a1[3]*z3;
      oa2 += a2[0]*z0 + a2[1]*z1 + a2[2]*z2 + a2[3]*z3;
    }
    bf16h* dst = (bf16h*)(ws + OFF_CATB) + (size_t)i*OUTD + 576;
    dst[(h0+0)*CZD + c] = __float2bfloat16(oa0);
    dst[(h0+1)*CZD + c] = __float2bfloat16(oa1);
    dst[(h0+2)*CZD + c] = __float2bfloat16(oa2);
  }

  // ---- phase 3b: o (t<192, from V) and o_pt (192<=t<480, from VP) ----
  {
    float ob = 0.f;
    int hsel = 0, off = 0, stride = 0;
    const float* src = ws;
    if (t < 192)      { hsel = t >> 4;      src = ws + OFF_V;  off = t;     stride = HC;  }
    else if (t < 480) { hsel = (t-192)/24;  src = ws + OFF_VP; off = t-192; stride = 288; }
    if (t < 480) {
      #pragma unroll 2
      for (int jj = 0; jj < NN; jj += 4) {
        f32x4 av = *(const f32x4*)(&AL(hsel, jj));
        float v0 = src[(size_t)(jj+0)*stride + off];
        float v1 = src[(size_t)(jj+1)*stride + off];
        float v2 = src[(size_t)(jj+2)*stride + off];
        float v3 = src[(size_t)(jj+3)*stride + off];
        ob += av[0]*v0 + av[1]*v1 + av[2]*v2 + av[3]*v3;
      }
    }
    bf16h* catb = (bf16h*)(ws + OFF_CATB);
    if (t < 192)      catb[(size_t)i*OUTD + t] = __float2bfloat16(ob);
    else if (t < 480) optl[t-192] = ob;
    __syncthreads();
    if (t < 96) {
      const int m = t, h = m >> 3;
      float g[3], Tl[3];
      #pragma unroll
      for (int y = 0; y < 3; ++y) { g[y] = optl[h*24 + (m&7)*3 + y]; Tl[y] = trans[i*3+y]; }
      float nrm = 1e-8f;
      float loc[3];
      #pragma unroll
      for (int x = 0; x < 3; ++x) {
        float v = 0.f;
        #pragma unroll
        for (int y = 0; y < 3; ++y) v += rot[i*9 + y*3 + x] * (g[y]-Tl[y]);
        loc[x] = v; nrm += v*v;
      }
      nrm = sqrtf(nrm);
      bf16h* crow = catb + (size_t)i*OUTD;
      crow[192 + 0*96 + m] = __float2bfloat16(loc[0]);
      crow[192 + 1*96 + m] = __float2bfloat16(loc[1]);
      crow[192 + 2*96 + m] = __float2bfloat16(loc[2]);
      crow[480 + m]        = __float2bfloat16(nrm);
    }
  }
  #undef AL
}

// ---------------- Kernel F: out = catb @ WoutT^T + bout via MFMA ----------------
__global__ __launch_bounds__(256) void k_out_mfma(
    const float* __restrict__ bout, const float* __restrict__ ws_c, float* __restrict__ out)
{
  const bf16h* catb  = (const bf16h*)(ws_c + OFF_CATB);
  const bf16h* woutT = (const bf16h*)(ws_c + OFF_WOT);
  const int t = threadIdx.x;
  const int wave = t >> 6, lane = t & 63;
  const int m0 = blockIdx.x*32 + (wave>>1)*16;
  const int n0 = blockIdx.y*32 + (wave&1)*16;
  const int lm = lane & 15, quad = lane >> 4;
  const bf16x8* pa = (const bf16x8*)(catb  + (size_t)(m0+lm)*OUTD) + quad;
  const bf16x8* pb = (const bf16x8*)(woutT + (size_t)(n0+lm)*OUTD) + quad;
  f32x4 acc = {0.f, 0.f, 0.f, 0.f};
  #pragma unroll 4
  for (int kk = 0; kk < OUTD/32; ++kk) {
    bf16x8 av = pa[kk*4];
    bf16x8 bv = pb[kk*4];
    acc = __builtin_amdgcn_mfma_f32_16x16x32_bf16(av, bv, acc, 0, 0, 0);
  }
  const int col = n0 + lm;
  const float bb = bout[col];
  #pragma unroll
  for (int r = 0; r < 4; ++r) {
    int row = m0 + quad*4 + r;
    out[(size_t)row*CSD + col] = acc[r] + bb;
  }
}

extern "C" void kernel_launch(void* const* d_in, const int* in_sizes, int n_in,
                              void* d_out, int out_size, void* d_ws, size_t ws_size,
                              hipStream_t stream)
{
  const float* s     = (const float*)d_in[0];
  const float* z     = (const float*)d_in[1];
  const float* rot   = (const float*)d_in[2];
  const float* trans = (const float*)d_in[3];
  const float* mask  = (const float*)d_in[4];
  const float* Wq    = (const float*)d_in[5];
  const float* bq    = (const float*)d_in[6];
  const float* Wkv   = (const float*)d_in[7];
  const float* bkv   = (const float*)d_in[8];
  const float* Wqp   = (const float*)d_in[9];
  const float* bqp   = (const float*)d_in[10];
  const float* Wkvp  = (const float*)d_in[11];
  const float* bkvp  = (const float*)d_in[12];
  const float* Wb    = (const float*)d_in[13];
  const float* bb    = (const float*)d_in[14];
  const float* hwts  = (const float*)d_in[15];
  const float* Wout  = (const float*)d_in[16];
  const float* bout  = (const float*)d_in[17];
  float* ws  = (float*)d_ws;
  float* out = (float*)d_out;

  hipLaunchKernelGGL(k_wcat, dim3(WCAT_BLOCKS), dim3(256), 0, stream,
                     s, Wq, bq, Wkv, bkv, Wqp, bqp, Wkvp, bkvp, Wout, ws);
  hipLaunchKernelGGL(k_proj_gemm, dim3(NN/32, NPROJ/32), dim3(256), 0, stream, ws);
  hipLaunchKernelGGL(k_proj_epi,  dim3(NN/RPB), dim3(256), 0, stream, rot, trans, ws);
  hipLaunchKernelGGL(k_row, dim3(NN), dim3(512), 0, stream,
                     z, Wb, bb, mask, hwts, rot, trans, ws);
  hipLaunchKernelGGL(k_out_mfma, dim3(NN/32, CSD/32), dim3(256), 0, stream, bout, ws, out);
}

// Round 8
// 319.108 us; speedup vs baseline: 1.1730x; 1.0395x over previous
//
#include <hip/hip_runtime.h>
#include <hip/hip_bf16.h>

typedef __hip_bfloat16 bf16h;
typedef short bf16x8 __attribute__((ext_vector_type(8)));
typedef float f32x4 __attribute__((ext_vector_type(4)));

#define NH 12
#define CHD 16
#define PQN 4
#define PVN 8
#define CSD 384
#define CZD 128
#define NN 512
#define HC 192
#define OUTD 2112
#define NSQ (NN*NN)
#define NPROJ 1152

// ws layout (float offsets). RAW/SB/WCT are consumed by k_proj_epi before k_row
// runs. Scores live entirely in LDS inside k_row (no HBM round-trip).
// K and KP are stored TRANSPOSED ([h][c][j]) so k_row phase-2 reads coalesce.
#define OFF_Q    0u
#define OFF_K    98304u      /* f32 [12][16][512] = 98304 floats (transposed) */
#define OFF_V    196608u     /* f32 [n][h*16+c] row-major (phase-3b coalesced) */
#define OFF_QP   294912u     /* f32 [n][144] */
#define OFF_KP   368640u     /* f32 [12][12][512] = 73728 floats (transposed) */
#define OFF_VP   442368u     /* f32 [n][288] */
#define OFF_RAW  589824u     /* f32 512x1152 = 589824 floats -> ends 1179648 */
#define OFF_SB   1179648u    /* bf16 512x384  = 98304 floats -> ends 1277952 */
#define OFF_WCT  1277952u    /* bf16 1152x384 = 221184 floats -> ends 1499136 */
#define OFF_CATB 3735552u    /* bf16 512x2112 = 540672 floats */
#define OFF_WOT  4276224u    /* bf16 384x2112 = 405504 floats */
#define OFF_BCAT 4681728u    /* f32 1152 -> end 4682880 floats = 18.73 MB */

// k_wcat block budget: 432 WCT tiles + 792 WoutT tiles + 128 s-pack + 1 bias
#define NT_WCT  432          /* (NPROJ/32)*(CSD/32) */
#define NT_WOUT 792          /* (OUTD/32)*(CSD/32)  */
#define WCAT_BLOCKS (NT_WCT + NT_WOUT + 128 + 1)

__device__ inline short f2bf(float x) {
  bf16h b = __float2bfloat16(x);
  short s;
  __builtin_memcpy(&s, &b, 2);
  return s;
}

// ---------------- Kernel W1: pack weights/s to bf16 (LDS-tiled transposes) ----------------
// R4 lesson: the Wqp/Wkvp boundary (col 720) is NOT 32-aligned -> matrix
// selection must be per-COLUMN (per-lane), not per-tile.
__global__ __launch_bounds__(256) void k_wcat(
    const float* __restrict__ s,
    const float* __restrict__ Wq, const float* __restrict__ bq,
    const float* __restrict__ Wkv, const float* __restrict__ bkv,
    const float* __restrict__ Wqp, const float* __restrict__ bqp,
    const float* __restrict__ Wkvp, const float* __restrict__ bkvp,
    const float* __restrict__ Wout, float* __restrict__ ws)
{
  __shared__ float tile[32][33];
  const int b = blockIdx.x, t = threadIdx.x;
  const int tx = t & 31, ty = t >> 5;        // 32 x 8
  if (b < NT_WCT) {
    // WcatT[col][c] = W[c][colW], tiles of 32 cols x 32 c
    const int ct = b / 12, rt = b % 12;
    const int col0 = ct*32, c0 = rt*32;
    const int col = col0 + tx;               // per-lane matrix select (720 boundary!)
    const float* W; int ld, colW;
    if (col < 192)      { W = Wq;   ld = 192; colW = col; }
    else if (col < 576) { W = Wkv;  ld = 384; colW = col-192; }
    else if (col < 720) { W = Wqp;  ld = 144; colW = col-576; }
    else                { W = Wkvp; ld = 432; colW = col-720; }
    #pragma unroll
    for (int r = 0; r < 4; ++r)
      tile[ty + r*8][tx] = W[(size_t)(c0 + ty + r*8)*ld + colW];
    __syncthreads();
    bf16h* dstW = (bf16h*)(ws + OFF_WCT);
    #pragma unroll
    for (int r = 0; r < 4; ++r) {
      int colL = ty + r*8;
      dstW[(size_t)(col0 + colL)*CSD + c0 + tx] = __float2bfloat16(tile[tx][colL]);
    }
  } else if (b < NT_WCT + NT_WOUT) {
    // WoutT[n][k] = Wout[k][n], tiles of 32 k x 32 n
    const int q = b - NT_WCT;
    const int kt = q / 12, nt2 = q % 12;
    const int k0 = kt*32, n0 = nt2*32;
    #pragma unroll
    for (int r = 0; r < 4; ++r)
      tile[ty + r*8][tx] = Wout[(size_t)(k0 + ty + r*8)*CSD + n0 + tx];
    __syncthreads();
    bf16h* woutT = (bf16h*)(ws + OFF_WOT);
    #pragma unroll
    for (int r = 0; r < 4; ++r) {
      int nL = ty + r*8;
      woutT[(size_t)(n0 + nL)*OUTD + k0 + tx] = __float2bfloat16(tile[tx][nL]);
    }
  } else if (b < NT_WCT + NT_WOUT + 128) {
    const int n0 = (b - (NT_WCT + NT_WOUT))*4;
    bf16h* sb = (bf16h*)(ws + OFF_SB);
    for (int idx = t; idx < 4*CSD; idx += 256)
      sb[(size_t)n0*CSD + idx] = __float2bfloat16(s[(size_t)n0*CSD + idx]);
  } else {
    float* bcat = ws + OFF_BCAT;
    for (int o = t; o < NPROJ; o += 256) {
      float v;
      if (o < 192)      v = bq[o];
      else if (o < 576) v = bkv[o-192];
      else if (o < 720) v = bqp[o-576];
      else              v = bkvp[o-720];
      bcat[o] = v;
    }
  }
}

// ---------------- Kernel A1: raw = sb @ WcatT^T via MFMA ----------------
__global__ __launch_bounds__(256) void k_proj_gemm(float* __restrict__ ws)
{
  const bf16h* sb    = (const bf16h*)(ws + OFF_SB);
  const bf16h* wcatT = (const bf16h*)(ws + OFF_WCT);
  float* raw = ws + OFF_RAW;
  const int t = threadIdx.x;
  const int wave = t >> 6, lane = t & 63;
  const int m0 = blockIdx.x*32 + (wave>>1)*16;
  const int n0 = blockIdx.y*32 + (wave&1)*16;
  const int lm = lane & 15, quad = lane >> 4;
  const bf16x8* pa = (const bf16x8*)(sb    + (size_t)(m0+lm)*CSD) + quad;
  const bf16x8* pb = (const bf16x8*)(wcatT + (size_t)(n0+lm)*CSD) + quad;
  f32x4 acc = {0.f, 0.f, 0.f, 0.f};
  #pragma unroll
  for (int kk = 0; kk < CSD/32; ++kk) {
    bf16x8 av = pa[kk*4];
    bf16x8 bv = pb[kk*4];
    acc = __builtin_amdgcn_mfma_f32_16x16x32_bf16(av, bv, acc, 0, 0, 0);
  }
  const int col = n0 + lm;
  #pragma unroll
  for (int r = 0; r < 4; ++r) {
    int row = m0 + quad*4 + r;
    raw[(size_t)row*NPROJ + col] = acc[r];
  }
}

// ---------------- Kernel A2: bias + scatter + point rotation (4 rows/block) ----------------
// K and KP written TRANSPOSED: KT[(h*16+c)*512 + n], KPT[((h*4+p)*3+x)*512 + n]
// so k_row phase-2 per-thread (j=t) reads are wave-coalesced.
#define RPB 4
__global__ __launch_bounds__(256) void k_proj_epi(
    const float* __restrict__ rot, const float* __restrict__ trans,
    float* __restrict__ ws)
{
  __shared__ float praw[RPB][576];
  const int n0 = blockIdx.x*RPB, t = threadIdx.x;
  const float* raw = ws + OFF_RAW;
  const float* bcat = ws + OFF_BCAT;
  for (int idx = t; idx < RPB*NPROJ; idx += 256) {
    int r = idx / NPROJ, o = idx - r*NPROJ;
    int n = n0 + r;
    float v = raw[(size_t)n*NPROJ + o] + bcat[o];
    if (o < 192) {
      ws[OFF_Q + n*HC + o] = v;
    } else if (o < 576) {
      int col = o-192, h = col >> 5, rr = col & 31;
      if (rr < CHD) ws[OFF_K + (size_t)(h*CHD + rr)*NN + n] = v;   // transposed
      else          ws[OFF_V + n*HC + h*CHD + (rr-CHD)] = v;
    } else {
      praw[r][o-576] = v;
    }
  }
  __syncthreads();
  for (int m2 = t; m2 < RPB*192; m2 += 256) {
    int r = m2 / 192, m = m2 % 192;
    int n = n0 + r;
    float g0, g1, g2;
    if (m < 48) {
      g0 = praw[r][m]; g1 = praw[r][48+m]; g2 = praw[r][96+m];
      int h = m >> 2, p = m & 3;
      float* dst = ws + OFF_QP + ((size_t)n*NH+h)*PQN*3 + p*3;
      #pragma unroll
      for (int x = 0; x < 3; ++x)
        dst[x] = rot[n*9+x*3+0]*g0 + rot[n*9+x*3+1]*g1 + rot[n*9+x*3+2]*g2 + trans[n*3+x];
    } else {
      int mm = m - 48;
      g0 = praw[r][144+mm]; g1 = praw[r][288+mm]; g2 = praw[r][432+mm];
      int h = mm / 12, pp = mm % 12;
      if (pp < PQN) {
        #pragma unroll
        for (int x = 0; x < 3; ++x)
          ws[OFF_KP + (size_t)((h*PQN + pp)*3 + x)*NN + n] =       // transposed
            rot[n*9+x*3+0]*g0 + rot[n*9+x*3+1]*g1 + rot[n*9+x*3+2]*g2 + trans[n*3+x];
      } else {
        float* dst = ws + OFF_VP + ((size_t)n*NH+h)*PVN*3 + (pp-PQN)*3;
        #pragma unroll
        for (int x = 0; x < 3; ++x)
          dst[x] = rot[n*9+x*3+0]*g0 + rot[n*9+x*3+1]*g1 + rot[n*9+x*3+2]*g2 + trans[n*3+x];
      }
    }
  }
}

// ---------------- Kernel R: full per-row pipeline ----------------
// One block per row i, 512 threads.
// R7 lesson: phase 3a's broadcast ds_read_b128 of `a` was ~30us of LDS pipe.
// o_pair IS a matmul A(12x512)·Z(512x128) -> now MFMA 16x16x32 bf16:
// phase 2 stores a bf16 copy of `a` in fragment layout absm[16][520]
// (stride 520 -> uniform 8 words/bank on b128 A-frag reads); each of the
// 8 waves owns one 16-channel n-tile, B-frags gathered from global z.
__global__ __launch_bounds__(512) void k_row(
    const float* __restrict__ z, const float* __restrict__ Wb, const float* __restrict__ bbp,
    const float* __restrict__ mask, const float* __restrict__ head_w,
    const float* __restrict__ rot, const float* __restrict__ trans,
    float* __restrict__ ws)
{
  __shared__ float uzt[512*17];    // phase1: zt[row][17]; phase2/3b: a[h][520] f32
  __shared__ bf16h absm[16][520];  // phase3a: a bf16, MFMA A-fragment layout
  __shared__ float ql[HC];
  __shared__ float qpl[144];
  __shared__ float hwl[NH];
  __shared__ float redM[NH][8];
  __shared__ float redS[NH][8];
  __shared__ float optl[288];
  const int t = threadIdx.x, i = blockIdx.x;
  const int wave = t >> 6, lane = t & 63;

  if (t < HC)           ql[t]     = ws[OFF_Q  + (size_t)i*HC  + t];
  else if (t < HC+144)  qpl[t-HC] = ws[OFF_QP + (size_t)i*144 + (t-HC)];
  else if (t >= 352 && t < 352+NH)
    hwl[t-352] = log1pf(expf(head_w[t-352])) * 0.13608276348795434f; // softplus*sqrt(1/54)

  // ---- phase 1: b_pair accumulation (z HBM stream, 8 chunks x 16 ch) ----
  float acc[NH];
  #pragma unroll
  for (int h = 0; h < NH; ++h) acc[h] = bbp[h];
  float4 pf[4];
  #pragma unroll
  for (int k = 0; k < 4; ++k) {
    int idx4 = k*512 + t;
    int row = idx4 >> 2, c4 = idx4 & 3;
    pf[k] = *(const float4*)(z + ((size_t)i*NN + row)*CZD + c4*4);
  }
  for (int cb = 0; cb < 8; ++cb) {
    __syncthreads();
    #pragma unroll
    for (int k = 0; k < 4; ++k) {
      int idx4 = k*512 + t;
      int row = idx4 >> 2, c4 = idx4 & 3;
      float* d = uzt + row*17 + c4*4;
      d[0]=pf[k].x; d[1]=pf[k].y; d[2]=pf[k].z; d[3]=pf[k].w;
    }
    __syncthreads();
    if (cb < 7) {
      #pragma unroll
      for (int k = 0; k < 4; ++k) {
        int idx4 = k*512 + t;
        int row = idx4 >> 2, c4 = idx4 & 3;
        pf[k] = *(const float4*)(z + ((size_t)i*NN + row)*CZD + (cb+1)*16 + c4*4);
      }
    }
    #pragma unroll
    for (int c = 0; c < 16; ++c) {
      float v = uzt[t*17 + c];
      const float* w = Wb + (cb*16+c)*NH;   // wave-uniform -> scalar loads
      #pragma unroll
      for (int h = 0; h < NH; ++h) acc[h] += v*w[h];
    }
  }

  // ---- phase 2: scores + softmax, 3 groups of 4 heads (6 barriers total) ----
  const float sc13  = 0.57735026918962576f;   // sqrt(1/3)
  const float sc_qk = 0.14433756729740643f;   // sqrt(1/48)
  const float mbias = 100000.0f*(mask[i]*mask[t] - 1.0f);
  #define AL(h,j) uzt[(h)*520 + (j)]
  for (int g = 0; g < 3; ++g) {
    float sc4[4];
    #pragma unroll
    for (int u = 0; u < 4; ++u) {
      const int h = g*4 + u;
      const float* kt  = ws + OFF_K  + (size_t)(h*CHD)*NN + t;   // coalesced columns
      const float* kpt = ws + OFF_KP + (size_t)(h*12)*NN + t;
      float dot = 0.f;
      #pragma unroll
      for (int c = 0; c < CHD; ++c) dot += ql[h*CHD+c]*kt[(size_t)c*NN];
      float d2 = 0.f;
      #pragma unroll
      for (int e = 0; e < 12; ++e) { float d = qpl[h*12+e]-kpt[(size_t)e*NN]; d2 += d*d; }
      float scv = dot*sc_qk + acc[h]*sc13 - 0.5f*hwl[h]*d2 + mbias;
      float mv = scv;
      for (int off = 32; off > 0; off >>= 1) mv = fmaxf(mv, __shfl_xor(mv, off));
      if (lane == 0) redM[h][wave] = mv;
      sc4[u] = scv;
    }
    __syncthreads();
    #pragma unroll
    for (int u = 0; u < 4; ++u) {
      const int h = g*4 + u;
      float mv = redM[h][0];
      #pragma unroll
      for (int w = 1; w < 8; ++w) mv = fmaxf(mv, redM[h][w]);
      float e = expf(sc4[u] - mv);
      sc4[u] = e;
      float sv = e;
      for (int off = 32; off > 0; off >>= 1) sv += __shfl_xor(sv, off);
      if (lane == 0) redS[h][wave] = sv;
    }
    __syncthreads();
    #pragma unroll
    for (int u = 0; u < 4; ++u) {
      const int h = g*4 + u;
      float sv = redS[h][0];
      #pragma unroll
      for (int w = 1; w < 8; ++w) sv += redS[h][w];
      float p = sc4[u]*(1.0f/sv);
      AL(h, t) = p;                       // f32 copy for phase 3b
      absm[h][t] = __float2bfloat16(p);   // bf16 fragment copy for phase 3a MFMA
    }
  }
  __syncthreads();                   // a fully written before cross-thread reads

  // ---- phase 3a (MFMA): o_pair[h][c] = sum_j a[h][j]*z[i][j][c] ----
  // A = absm (16 heads-padded x 512), B = z-row-block (512 x 128), one
  // 16-channel n-tile per wave. Rows 12-15 of A are garbage -> discarded.
  {
    const int n0 = wave*16;
    const int lm = lane & 15, quad = lane >> 4;
    f32x4 oacc = {0.f, 0.f, 0.f, 0.f};
    const float* zcol = z + (size_t)i*NN*CZD + n0 + lm;
    #pragma unroll 4
    for (int kk = 0; kk < 16; ++kk) {
      bf16x8 afrag = *(const bf16x8*)(&absm[lm][kk*32 + quad*8]);
      const float* zp = zcol + (size_t)(kk*32 + quad*8)*CZD;
      bf16x8 bfrag;
      #pragma unroll
      for (int jj = 0; jj < 8; ++jj)
        bfrag[jj] = f2bf(zp[(size_t)jj*CZD]);
      oacc = __builtin_amdgcn_mfma_f32_16x16x32_bf16(afrag, bfrag, oacc, 0, 0, 0);
    }
    if (quad < 3) {
      bf16h* dst = (bf16h*)(ws + OFF_CATB) + (size_t)i*OUTD + 576;
      #pragma unroll
      for (int r = 0; r < 4; ++r) {
        int h = quad*4 + r;
        dst[h*CZD + n0 + lm] = __float2bfloat16(oacc[r]);
      }
    }
  }

  // ---- phase 3b: o (t<192, from V) and o_pt (192<=t<480, from VP) ----
  {
    float ob = 0.f;
    int hsel = 0, off = 0, stride = 0;
    const float* src = ws;
    if (t < 192)      { hsel = t >> 4;      src = ws + OFF_V;  off = t;     stride = HC;  }
    else if (t < 480) { hsel = (t-192)/24;  src = ws + OFF_VP; off = t-192; stride = 288; }
    if (t < 480) {
      #pragma unroll 2
      for (int jj = 0; jj < NN; jj += 4) {
        f32x4 av = *(const f32x4*)(&AL(hsel, jj));
        float v0 = src[(size_t)(jj+0)*stride + off];
        float v1 = src[(size_t)(jj+1)*stride + off];
        float v2 = src[(size_t)(jj+2)*stride + off];
        float v3 = src[(size_t)(jj+3)*stride + off];
        ob += av[0]*v0 + av[1]*v1 + av[2]*v2 + av[3]*v3;
      }
    }
    bf16h* catb = (bf16h*)(ws + OFF_CATB);
    if (t < 192)      catb[(size_t)i*OUTD + t] = __float2bfloat16(ob);
    else if (t < 480) optl[t-192] = ob;
    __syncthreads();
    if (t < 96) {
      const int m = t, h = m >> 3;
      float g[3], Tl[3];
      #pragma unroll
      for (int y = 0; y < 3; ++y) { g[y] = optl[h*24 + (m&7)*3 + y]; Tl[y] = trans[i*3+y]; }
      float nrm = 1e-8f;
      float loc[3];
      #pragma unroll
      for (int x = 0; x < 3; ++x) {
        float v = 0.f;
        #pragma unroll
        for (int y = 0; y < 3; ++y) v += rot[i*9 + y*3 + x] * (g[y]-Tl[y]);
        loc[x] = v; nrm += v*v;
      }
      nrm = sqrtf(nrm);
      bf16h* crow = catb + (size_t)i*OUTD;
      crow[192 + 0*96 + m] = __float2bfloat16(loc[0]);
      crow[192 + 1*96 + m] = __float2bfloat16(loc[1]);
      crow[192 + 2*96 + m] = __float2bfloat16(loc[2]);
      crow[480 + m]        = __float2bfloat16(nrm);
    }
  }
  #undef AL
}

// ---------------- Kernel F: out = catb @ WoutT^T + bout via MFMA ----------------
__global__ __launch_bounds__(256) void k_out_mfma(
    const float* __restrict__ bout, const float* __restrict__ ws_c, float* __restrict__ out)
{
  const bf16h* catb  = (const bf16h*)(ws_c + OFF_CATB);
  const bf16h* woutT = (const bf16h*)(ws_c + OFF_WOT);
  const int t = threadIdx.x;
  const int wave = t >> 6, lane = t & 63;
  const int m0 = blockIdx.x*32 + (wave>>1)*16;
  const int n0 = blockIdx.y*32 + (wave&1)*16;
  const int lm = lane & 15, quad = lane >> 4;
  const bf16x8* pa = (const bf16x8*)(catb  + (size_t)(m0+lm)*OUTD) + quad;
  const bf16x8* pb = (const bf16x8*)(woutT + (size_t)(n0+lm)*OUTD) + quad;
  f32x4 acc = {0.f, 0.f, 0.f, 0.f};
  #pragma unroll 4
  for (int kk = 0; kk < OUTD/32; ++kk) {
    bf16x8 av = pa[kk*4];
    bf16x8 bv = pb[kk*4];
    acc = __builtin_amdgcn_mfma_f32_16x16x32_bf16(av, bv, acc, 0, 0, 0);
  }
  const int col = n0 + lm;
  const float bb = bout[col];
  #pragma unroll
  for (int r = 0; r < 4; ++r) {
    int row = m0 + quad*4 + r;
    out[(size_t)row*CSD + col] = acc[r] + bb;
  }
}

extern "C" void kernel_launch(void* const* d_in, const int* in_sizes, int n_in,
                              void* d_out, int out_size, void* d_ws, size_t ws_size,
                              hipStream_t stream)
{
  const float* s     = (const float*)d_in[0];
  const float* z     = (const float*)d_in[1];
  const float* rot   = (const float*)d_in[2];
  const float* trans = (const float*)d_in[3];
  const float* mask  = (const float*)d_in[4];
  const float* Wq    = (const float*)d_in[5];
  const float* bq    = (const float*)d_in[6];
  const float* Wkv   = (const float*)d_in[7];
  const float* bkv   = (const float*)d_in[8];
  const float* Wqp   = (const float*)d_in[9];
  const float* bqp   = (const float*)d_in[10];
  const float* Wkvp  = (const float*)d_in[11];
  const float* bkvp  = (const float*)d_in[12];
  const float* Wb    = (const float*)d_in[13];
  const float* bb    = (const float*)d_in[14];
  const float* hwts  = (const float*)d_in[15];
  const float* Wout  = (const float*)d_in[16];
  const float* bout  = (const float*)d_in[17];
  float* ws  = (float*)d_ws;
  float* out = (float*)d_out;

  hipLaunchKernelGGL(k_wcat, dim3(WCAT_BLOCKS), dim3(256), 0, stream,
                     s, Wq, bq, Wkv, bkv, Wqp, bqp, Wkvp, bkvp, Wout, ws);
  hipLaunchKernelGGL(k_proj_gemm, dim3(NN/32, NPROJ/32), dim3(256), 0, stream, ws);
  hipLaunchKernelGGL(k_proj_epi,  dim3(NN/RPB), dim3(256), 0, stream, rot, trans, ws);
  hipLaunchKernelGGL(k_row, dim3(NN), dim3(512), 0, stream,
                     z, Wb, bb, mask, hwts, rot, trans, ws);
  hipLaunchKernelGGL(k_out_mfma, dim3(NN/32, CSD/32), dim3(256), 0, stream, bout, ws, out);
}